// Round 5
// baseline (152.495 us; speedup 1.0000x reference)
//
#include <hip/hip_runtime.h>
#include <hip/hip_bf16.h>
#include <math.h>

#define B_N 4096
#define D_N 768
#define C_N 10

typedef float f32x4 __attribute__((ext_vector_type(4)));
typedef unsigned char uchar;

// Self-cleaning module-scope accumulators (immune to the harness's d_ws poison;
// all-zero invariant restored at the end of every launch).
// float index map:
//   [0] ce_sum   [2] tals   [3] nvalid
//   [8..18)   counts[10]
//   [20..28)  taml partial sums (8 slots, contention-spread)
//   [32..7712)  class sums [10][768]
//   [7936..7944) finish sub-counters (uint), [7944] finish master
//   [7952..7960) arrive sub-counters (uint), [7960] arrive master
__device__ float g_ws[8192];

typedef __attribute__((address_space(1))) const void gvoid;
typedef __attribute__((address_space(3))) void lvoid;

static __device__ __forceinline__ void gl2lds16(const void* g, void* l) {
    __builtin_amdgcn_global_load_lds((gvoid*)g, (lvoid*)l, 16, 0, 0);
}

// finish: hierarchical end-counter; last block writes output and re-zeroes scalars.
static __device__ __forceinline__ void finish(float* __restrict__ out, int t, int id) {
    if (t == 0) {
        __threadfence();
        int c = id & 7;
        unsigned int quota = (c == 0) ? 67u : 66u;   // 529 blocks
        unsigned int p = atomicAdd((unsigned int*)&g_ws[7936 + c], 1u);
        if (p == quota - 1u) {
            unsigned int pm = atomicAdd((unsigned int*)&g_ws[7944], 1u);
            if (pm == 7u) {
                __threadfence();
                float ces  = atomicAdd(&g_ws[0], 0.0f);
                float tals = atomicAdd(&g_ws[2], 0.0f);
                float nv   = atomicAdd(&g_ws[3], 0.0f);
                float tsum = 0.f;
#pragma unroll
                for (int i = 0; i < 8; ++i) tsum += atomicAdd(&g_ws[20 + i], 0.0f);
                float ce   = ces / (float)B_N;
                float taml = tsum / fmaxf(nv, 1.0f);
                out[0] = ce + 0.5f * tals + 0.5f * taml;
                out[1] = ce;
                out[2] = tals;
                out[3] = taml;
                // restore all-zero invariant (class sums/counts zeroed by TALS block)
#pragma unroll
                for (int i = 0; i < 8; ++i) g_ws[i] = 0.f;
#pragma unroll
                for (int i = 0; i < 8; ++i) g_ws[20 + i] = 0.f;
#pragma unroll
                for (int i = 0; i < 9; ++i) g_ws[7936 + i] = 0.f;
#pragma unroll
                for (int i = 0; i < 9; ++i) g_ws[7952 + i] = 0.f;
            }
        }
    }
}

// ---------------- ONE persistent kernel: prep -> soft grid barrier -> TALS/GEMM ----------------
// 529 blocks, provably co-resident (LDS ~50.9KB -> 3 blocks/CU; 529 <= 768), so the
// soft barrier cannot deadlock. Phase A by id: [0,16) CE | [16,208) class sums |
// [208,529) enorm (13 rows each). Phase B by id: 0 = TALS; 1..528 = 128x128 fp8 GEMM
// tiles (BK=64, 3-deep counted-vmcnt pipeline, XOR slot swizzle), then finish().
__global__ __launch_bounds__(256, 3) void k_all(const float* __restrict__ logits,
                                                const int* __restrict__ labels,
                                                const float* __restrict__ emb,
                                                const float* __restrict__ topo,
                                                uchar* __restrict__ enorm,
                                                float* __restrict__ out) {
    __shared__ __align__(16) uchar smem[49152];   // GEMM bufs; CE overlays ls in [0,10240)
    __shared__ int lA[128], lB[128];
    __shared__ float topo_s[C_N * C_N];
    __shared__ float wsum[4];
    __shared__ float ed[112];
    __shared__ float cnt_s[C_N];
    __shared__ float red[256];
    __shared__ float cnt[C_N];

    int t = threadIdx.x;
    int w = t >> 6, lane = t & 63;
    int id = blockIdx.x;

    // ================= PHASE A: prep =================
    if (id < 16) {
        // ---- CE + label histogram (rows id*256 .. +255) ----
        float* ls = (float*)smem;   // 2560 floats staged coalesced
        if (t < C_N) cnt[t] = 0.f;
        const float4* g4 = (const float4*)logits + id * 640;
        float4* l4 = (float4*)ls;
        l4[t] = g4[t];
        l4[t + 256] = g4[t + 256];
        if (t < 128) l4[t + 512] = g4[t + 512];
        __syncthreads();
        int row = id * 256 + t;
        int lab = labels[row];
        const float* lp = ls + t * C_N;
        float m = lp[0];
#pragma unroll
        for (int c = 1; c < C_N; ++c) m = fmaxf(m, lp[c]);
        float s = 0.f;
#pragma unroll
        for (int c = 0; c < C_N; ++c) s += __expf(lp[c] - m);
        float val = (m + __logf(s)) - lp[lab];
        atomicAdd(&cnt[lab], 1.0f);
        red[t] = val;
        __syncthreads();
        for (int off = 128; off; off >>= 1) {
            if (t < off) red[t] += red[t + off];
            __syncthreads();
        }
        if (t == 0) atomicAdd(&g_ws[0], red[0]);
        if (t < C_N) atomicAdd(&g_ws[8 + t], cnt[t]);
    } else if (id < 208) {
        // ---- class segment sums ----
        int bx = (id - 16) % 3, by = (id - 16) / 3;
        int col = bx * 256 + t;
        int rbase = by * 64;
        float a[C_N];
#pragma unroll
        for (int c = 0; c < C_N; ++c) a[c] = 0.f;
        const float* p = emb + (size_t)rbase * D_N + col;
#pragma unroll 4
        for (int rr = 0; rr < 64; ++rr) {
            int lab = labels[rbase + rr];
            float v = p[(size_t)rr * D_N];
#pragma unroll
            for (int c = 0; c < C_N; ++c) a[c] += (lab == c) ? v : 0.f;
        }
        float* sums = g_ws + 32;
#pragma unroll
        for (int c = 0; c < C_N; ++c) atomicAdd(&sums[c * D_N + col], a[c]);
    } else {
        // ---- enorm: rows [(id-208)*13, +13), wave w takes rr = w, w+4, w+8, w+12 ----
        int base = (id - 208) * 13;
        for (int rr = w; rr < 13; rr += 4) {
            int row = base + rr;
            if (row >= B_N) break;
            const float4* src = (const float4*)(emb + (size_t)row * D_N);
            float4 x0 = src[lane];
            float4 x1 = src[lane + 64];
            float4 x2 = src[lane + 128];
            float ss = x0.x * x0.x + x0.y * x0.y + x0.z * x0.z + x0.w * x0.w
                     + x1.x * x1.x + x1.y * x1.y + x1.z * x1.z + x1.w * x1.w
                     + x2.x * x2.x + x2.y * x2.y + x2.z * x2.z + x2.w * x2.w;
#pragma unroll
            for (int off = 32; off; off >>= 1) ss += __shfl_xor(ss, off, 64);
            float inv = 1.0f / fmaxf(sqrtf(ss), 1e-12f);
            int p0 = 0, p1 = 0, p2 = 0;
            p0 = __builtin_amdgcn_cvt_pk_fp8_f32(x0.x * inv, x0.y * inv, p0, false);
            p0 = __builtin_amdgcn_cvt_pk_fp8_f32(x0.z * inv, x0.w * inv, p0, true);
            p1 = __builtin_amdgcn_cvt_pk_fp8_f32(x1.x * inv, x1.y * inv, p1, false);
            p1 = __builtin_amdgcn_cvt_pk_fp8_f32(x1.z * inv, x1.w * inv, p1, true);
            p2 = __builtin_amdgcn_cvt_pk_fp8_f32(x2.x * inv, x2.y * inv, p2, false);
            p2 = __builtin_amdgcn_cvt_pk_fp8_f32(x2.z * inv, x2.w * inv, p2, true);
            unsigned int* dst = (unsigned int*)(enorm + (size_t)row * D_N);
            dst[lane]       = (unsigned int)p0;
            dst[lane + 64]  = (unsigned int)p1;
            dst[lane + 128] = (unsigned int)p2;
        }
    }

    // ================= soft grid barrier (hierarchical arrive + load-spin) =================
    __syncthreads();
    if (t == 0) {
        __threadfence();   // release phase-A stores device-wide
        int c = id & 7;
        unsigned int quota = (c == 0) ? 67u : 66u;
        if (atomicAdd((unsigned int*)&g_ws[7952 + c], 1u) == quota - 1u)
            atomicAdd((unsigned int*)&g_ws[7960], 1u);
        int poll = 0;
        while (__hip_atomic_load((unsigned int*)&g_ws[7960], __ATOMIC_RELAXED,
                                 __HIP_MEMORY_SCOPE_AGENT) != 8u) {
            __builtin_amdgcn_s_sleep(2);
            // rare RMW fallback: guaranteed-coherent read, deadlock insurance only
            if ((++poll & 255) == 0 &&
                atomicAdd((unsigned int*)&g_ws[7960], 0u) == 8u) break;
        }
        __threadfence();   // acquire all phase-A stores
    }
    __syncthreads();

    // ================= PHASE B =================
    if (id == 0) {
        // ---- TALS ----
        float* cents = (float*)smem;
        const float* sums = g_ws + 32;
        if (t < C_N) cnt_s[t] = g_ws[8 + t];
        __syncthreads();
        for (int idx = t; idx < C_N * D_N; idx += 256) {
            int c = idx / D_N;
            cents[idx] = sums[idx] / fmaxf(cnt_s[c], 1.0f);
        }
        __syncthreads();
        // re-zero consumed sums/counts (overlapped with GEMM blocks)
        for (int idx = t; idx < C_N * D_N; idx += 256) g_ws[32 + idx] = 0.f;
        if (t < C_N) g_ws[8 + t] = 0.f;
        for (int pp = 0; pp < 25; ++pp) {
            int p = w * 25 + pp;
            int i = p / C_N, j = p - (p / C_N) * C_N;
            const float* ci = cents + i * D_N;
            const float* cj = cents + j * D_N;
            float s = 0.f;
            for (int d = lane; d < D_N; d += 64) {
                float diff = ci[d] - cj[d];
                s += diff * diff;
            }
#pragma unroll
            for (int off = 32; off; off >>= 1) s += __shfl_xor(s, off, 64);
            if (lane == 0) ed[p] = sqrtf(s + 1e-12f);
        }
        __syncthreads();
        if (w == 0) {
            float e0 = ed[lane];
            float e1 = (lane < 36) ? ed[lane + 64] : 0.f;
            float mx = fmaxf(e0, e1);
#pragma unroll
            for (int off = 32; off; off >>= 1) mx = fmaxf(mx, __shfl_xor(mx, off, 64));
            float inv = 1.0f / (mx + 1e-8f);
            float d0 = e0 * inv - topo[lane];
            float s = d0 * d0;
            if (lane < 36) {
                float d1 = e1 * inv - topo[lane + 64];
                s += d1 * d1;
            }
#pragma unroll
            for (int off = 32; off; off >>= 1) s += __shfl_xor(s, off, 64);
            if (lane == 0) {
                g_ws[2] = s * (1.0f / (C_N * C_N));
                float s2 = 0.f;
#pragma unroll
                for (int c = 0; c < C_N; ++c) s2 += cnt_s[c] * cnt_s[c];
                g_ws[3] = (float)B_N * (float)B_N - s2;
            }
        }
        __syncthreads();
        finish(out, t, id);
        return;
    }

    // ---- GEMM tile: triangle decode id-1 -> (bi, bj), bj >= bi ----
    int u = id - 1, bi = 0, rowlen = 32;
    while (u >= rowlen) { u -= rowlen; ++bi; --rowlen; }
    int bj = bi + u;

    int ib0 = bi * 128, jb0 = bj * 128;
    if (t < 128) lA[t] = labels[ib0 + t];
    else         lB[t - 128] = labels[jb0 + t - 128];
    if (t < C_N * C_N) topo_s[t] = topo[t];

    int quad = lane >> 4, m16 = lane & 15;
    int wrow = (w >> 1) * 64, wcol = (w & 1) * 64;

    f32x4 acc[4][4];
    f32x4 z = {0.f, 0.f, 0.f, 0.f};
#pragma unroll
    for (int mt = 0; mt < 4; ++mt)
#pragma unroll
        for (int nt = 0; nt < 4; ++nt) acc[mt][nt] = z;

    // staging: 8 chunks of 1KB per side per window (chunk = 16 rows x 64 B);
    // wave w owns chunks {w, w+4}. XOR slot swizzle both sides.
    int rl = lane >> 2, cs = lane & 3;
    int csw = (cs ^ ((rl >> 1) & 3)) * 16;
    const uchar* gA[2];
    const uchar* gB[2];
    int ldsoff[2];
#pragma unroll
    for (int h = 0; h < 2; ++h) {
        int chunk = w + 4 * h;
        gA[h] = enorm + (size_t)(ib0 + chunk * 16 + rl) * D_N + csw;
        gB[h] = enorm + (size_t)(jb0 + chunk * 16 + rl) * D_N + csw;
        ldsoff[h] = chunk * 1024;
    }

    // drain everything so vmcnt counts only window DMAs
    asm volatile("s_waitcnt vmcnt(0) lgkmcnt(0)" ::: "memory");
    __builtin_amdgcn_s_barrier();
    __builtin_amdgcn_sched_barrier(0);

    // prologue: issue K-windows 0..2
#pragma unroll
    for (int wv = 0; wv < 3; ++wv) {
#pragma unroll
        for (int h = 0; h < 2; ++h) {
            gl2lds16(gA[h] + wv * 64, smem + wv * 8192 + ldsoff[h]);
            gl2lds16(gB[h] + wv * 64, smem + 24576 + wv * 8192 + ldsoff[h]);
        }
    }

    int bufsel = 0;
    for (int kt = 0; kt < 12; ++kt) {
        if (kt < 10)       asm volatile("s_waitcnt vmcnt(8)" ::: "memory");
        else if (kt == 10) asm volatile("s_waitcnt vmcnt(4)" ::: "memory");
        else               asm volatile("s_waitcnt vmcnt(0)" ::: "memory");
        __builtin_amdgcn_s_barrier();
        __builtin_amdgcn_sched_barrier(0);

        const uchar* Ac = smem + bufsel * 8192;
        const uchar* Bc = smem + 24576 + bufsel * 8192;
#pragma unroll
        for (int ks = 0; ks < 2; ++ks) {
            int s = ks * 2 + (quad >> 1);
            int in8 = (quad & 1) * 8;
            long af[4], bfr[4];
#pragma unroll
            for (int x = 0; x < 4; ++x) {
                int rowA = wrow + x * 16 + m16;
                int rowB = wcol + x * 16 + m16;
                af[x]  = *(const long*)(Ac + rowA * 64 + ((s ^ ((rowA >> 1) & 3)) * 16) + in8);
                bfr[x] = *(const long*)(Bc + rowB * 64 + ((s ^ ((rowB >> 1) & 3)) * 16) + in8);
            }
#pragma unroll
            for (int mt = 0; mt < 4; ++mt)
#pragma unroll
                for (int nt = 0; nt < 4; ++nt)
                    acc[mt][nt] = __builtin_amdgcn_mfma_f32_16x16x32_fp8_fp8(
                        af[mt], bfr[nt], acc[mt][nt], 0, 0, 0);
        }

        __builtin_amdgcn_sched_barrier(0);
        __builtin_amdgcn_s_barrier();
        if (kt + 3 < 12) {
#pragma unroll
            for (int h = 0; h < 2; ++h) {
                gl2lds16(gA[h] + (kt + 3) * 64, smem + bufsel * 8192 + ldsoff[h]);
                gl2lds16(gB[h] + (kt + 3) * 64, smem + 24576 + bufsel * 8192 + ldsoff[h]);
            }
        }
        bufsel = (bufsel == 2) ? 0 : bufsel + 1;
    }

    // epilogue: relu(sim - 1 + margin) over valid (li!=lj) upper-tri pairs, x2
    float local = 0.f;
#pragma unroll
    for (int mt = 0; mt < 4; ++mt) {
#pragma unroll
        for (int nt = 0; nt < 4; ++nt) {
#pragma unroll
            for (int reg = 0; reg < 4; ++reg) {
                int il = wrow + mt * 16 + quad * 4 + reg;
                int jl = wcol + nt * 16 + m16;
                int gi = ib0 + il, gj = jb0 + jl;
                int li = lA[il], lj = lB[jl];
                float v = acc[mt][nt][reg] - 1.0f + topo_s[li * C_N + lj];
                if (li != lj && gi < gj && v > 0.f) local += v;
            }
        }
    }
    local *= 2.0f;

#pragma unroll
    for (int off = 32; off; off >>= 1) local += __shfl_down(local, off, 64);
    if (lane == 0) wsum[w] = local;
    __syncthreads();
    if (t == 0) atomicAdd(&g_ws[20 + (id & 7)], wsum[0] + wsum[1] + wsum[2] + wsum[3]);
    finish(out, t, id);
}

extern "C" void kernel_launch(void* const* d_in, const int* in_sizes, int n_in,
                              void* d_out, int out_size, void* d_ws, size_t ws_size,
                              hipStream_t stream) {
    const float* logits = (const float*)d_in[0];
    const int*   labels = (const int*)d_in[1];
    const float* emb    = (const float*)d_in[2];
    const float* topo   = (const float*)d_in[3];
    uchar* enorm = (uchar*)d_ws + 65536;
    float* out = (float*)d_out;

    k_all<<<529, 256, 0, stream>>>(logits, labels, emb, topo, enorm, out);
}

// Round 6
// 116.339 us; speedup vs baseline: 1.3108x; 1.3108x over previous
//
#include <hip/hip_runtime.h>
#include <hip/hip_bf16.h>
#include <math.h>

#define B_N 4096
#define D_N 768
#define C_N 10

typedef float f32x4 __attribute__((ext_vector_type(4)));
typedef unsigned char uchar;

// Self-cleaning module-scope accumulators (immune to the harness's d_ws poison;
// all-zero invariant restored by finish() at the end of every launch).
// float index map:
//   [0] ce_sum   [2] tals   [3] nvalid
//   [8..18)   counts[10]
//   [32..7712)  class sums [10][768]
//   [7760+16c] c=0..7: taml partial sums (64B-spread slots, no line sharing)
//   [7936..7944) finish sub-counters (uint), [7944] finish master
__device__ float g_ws[8192];

// d_ws byte offset 65536: enorm fp8 e4m3, FRAGMENT-TILED layout (3145728 bytes):
//   element (row r, k-byte kb) at (r & ~15)*768 + (kb>>3)*128 + (r&15)*8 + (kb&7)
// i.e. 16-row groups; within a group, 96 k-granules of 8B x 16 rows. A wave's
// MFMA fragment load (16 rows x 4 granules) is one contiguous 512B region.

// ---------------- merged prep: CE + histogram | class sums | row-normalize->fp8 ----------------
// blocks [0,16): CE; [16,208): class segment sums; [208,1232): enorm (wave/row)
__global__ void k_prep(const float* __restrict__ logits,
                       const int* __restrict__ labels,
                       const float* __restrict__ emb,
                       uchar* __restrict__ enorm) {
    __shared__ float red[256];
    __shared__ float cnt[C_N];
    __shared__ float ls[2560];                 // CE: 256x10 logits staged coalesced
    __shared__ __align__(8) unsigned int rowbuf[4 * 192];   // enorm: 4 waves x 768B bounce
    int bb = blockIdx.x;
    int t = threadIdx.x;

    if (bb < 16) {
        if (t < C_N) cnt[t] = 0.f;
        const float4* g4 = (const float4*)logits + bb * 640;
        float4* l4 = (float4*)ls;
        l4[t] = g4[t];
        l4[t + 256] = g4[t + 256];
        if (t < 128) l4[t + 512] = g4[t + 512];
        __syncthreads();
        int row = bb * 256 + t;
        int lab = labels[row];
        const float* lp = ls + t * C_N;        // stride-10 LDS read: 2-way alias, free
        float m = lp[0];
#pragma unroll
        for (int c = 1; c < C_N; ++c) m = fmaxf(m, lp[c]);
        float s = 0.f;
#pragma unroll
        for (int c = 0; c < C_N; ++c) s += __expf(lp[c] - m);
        float val = (m + __logf(s)) - lp[lab];
        atomicAdd(&cnt[lab], 1.0f);
        red[t] = val;
        __syncthreads();
        for (int off = 128; off; off >>= 1) {
            if (t < off) red[t] += red[t + off];
            __syncthreads();
        }
        if (t == 0) atomicAdd(&g_ws[0], red[0]);
        if (t < C_N) atomicAdd(&g_ws[8 + t], cnt[t]);
    } else if (bb < 208) {
        int bx = (bb - 16) % 3, by = (bb - 16) / 3;
        int col = bx * 256 + t;
        int rbase = by * 64;
        float a[C_N];
#pragma unroll
        for (int c = 0; c < C_N; ++c) a[c] = 0.f;
        const float* p = emb + (size_t)rbase * D_N + col;
#pragma unroll 4
        for (int rr = 0; rr < 64; ++rr) {
            int lab = labels[rbase + rr];
            float v = p[(size_t)rr * D_N];
#pragma unroll
            for (int c = 0; c < C_N; ++c) a[c] += (lab == c) ? v : 0.f;
        }
        float* sums = g_ws + 32;
#pragma unroll
        for (int c = 0; c < C_N; ++c) atomicAdd(&sums[c * D_N + col], a[c]);
    } else {
        int w = t >> 6, lane = t & 63;
        int row = (bb - 208) * 4 + w;
        const float4* src = (const float4*)(emb + (size_t)row * D_N);
        float4 x0 = src[lane];
        float4 x1 = src[lane + 64];
        float4 x2 = src[lane + 128];
        float ss = x0.x * x0.x + x0.y * x0.y + x0.z * x0.z + x0.w * x0.w
                 + x1.x * x1.x + x1.y * x1.y + x1.z * x1.z + x1.w * x1.w
                 + x2.x * x2.x + x2.y * x2.y + x2.z * x2.z + x2.w * x2.w;
#pragma unroll
        for (int off = 32; off; off >>= 1) ss += __shfl_xor(ss, off, 64);
        float inv = 1.0f / fmaxf(sqrtf(ss), 1e-12f);
        int p0 = 0, p1 = 0, p2 = 0;
        p0 = __builtin_amdgcn_cvt_pk_fp8_f32(x0.x * inv, x0.y * inv, p0, false);
        p0 = __builtin_amdgcn_cvt_pk_fp8_f32(x0.z * inv, x0.w * inv, p0, true);
        p1 = __builtin_amdgcn_cvt_pk_fp8_f32(x1.x * inv, x1.y * inv, p1, false);
        p1 = __builtin_amdgcn_cvt_pk_fp8_f32(x1.z * inv, x1.w * inv, p1, true);
        p2 = __builtin_amdgcn_cvt_pk_fp8_f32(x2.x * inv, x2.y * inv, p2, false);
        p2 = __builtin_amdgcn_cvt_pk_fp8_f32(x2.z * inv, x2.w * inv, p2, true);
        // bounce the 768B row through LDS, then scatter 8B granules to the
        // fragment-tiled global layout
        unsigned int* rb = rowbuf + w * 192;
        rb[lane]       = (unsigned int)p0;
        rb[lane + 64]  = (unsigned int)p1;
        rb[lane + 128] = (unsigned int)p2;
        asm volatile("s_waitcnt lgkmcnt(0)" ::: "memory");   // cross-lane LDS visibility
        uchar* gb = enorm + (size_t)(row & ~15) * D_N + (row & 15) * 8;
        uint2 v0 = ((const uint2*)rb)[lane];
        *(uint2*)(gb + (size_t)lane * 128) = v0;
        if (lane < 32) {
            uint2 v1 = ((const uint2*)rb)[64 + lane];
            *(uint2*)(gb + (size_t)(64 + lane) * 128) = v1;
        }
    }
}

// finish: hierarchical end-counter; last block writes output and re-zeroes scalars.
static __device__ __forceinline__ void finish(float* __restrict__ out, int t, int id) {
    if (t == 0) {
        __threadfence();
        int c = id & 7;
        unsigned int quota = (c == 0) ? 67u : 66u;   // 529 blocks
        unsigned int p = atomicAdd((unsigned int*)&g_ws[7936 + c], 1u);
        if (p == quota - 1u) {
            unsigned int pm = atomicAdd((unsigned int*)&g_ws[7944], 1u);
            if (pm == 7u) {
                __threadfence();
                float ces  = atomicAdd(&g_ws[0], 0.0f);
                float tals = atomicAdd(&g_ws[2], 0.0f);
                float nv   = atomicAdd(&g_ws[3], 0.0f);
                float tsum = 0.f;
#pragma unroll
                for (int i = 0; i < 8; ++i) tsum += atomicAdd(&g_ws[7760 + 16 * i], 0.0f);
                float ce   = ces / (float)B_N;
                float taml = tsum / fmaxf(nv, 1.0f);
                out[0] = ce + 0.5f * tals + 0.5f * taml;
                out[1] = ce;
                out[2] = tals;
                out[3] = taml;
                // restore all-zero invariant (class sums/counts zeroed by TALS block)
#pragma unroll
                for (int i = 0; i < 8; ++i) g_ws[i] = 0.f;
#pragma unroll
                for (int i = 0; i < 8; ++i) g_ws[7760 + 16 * i] = 0.f;
#pragma unroll
                for (int i = 0; i < 9; ++i) g_ws[7936 + i] = 0.f;
            }
        }
    }
}

// ---------------- TAML GEMM: register-direct fp8 MFMA, NO LDS staging, NO barriers ----------------
// 529 blocks: id 0 = TALS; id 1..528 = upper-tri 128x128 tiles. enorm (3MB) is
// L2-resident per XCD; the fragment-tiled layout makes every A/B fragment load one
// coalesced 512B global_load_dwordx2 per wave. K-loop = 24 x {8 loads, 16 MFMAs},
// latency hidden by TLP (4 waves/SIMD via launch_bounds) + compiler pipelining.
__global__ __launch_bounds__(256, 4) void k_taml(const uchar* __restrict__ E,
                                                 const int* __restrict__ labels,
                                                 const float* __restrict__ topo,
                                                 float* __restrict__ out) {
    __shared__ float cents[C_N * D_N];   // 30KB, TALS block only
    __shared__ int lA[128], lB[128];
    __shared__ float topo_s[C_N * C_N];
    __shared__ float wsum[4];
    __shared__ float ed[112];
    __shared__ float cnt_s[C_N];

    int t = threadIdx.x;
    int w = t >> 6, lane = t & 63;
    int id = blockIdx.x;

    if (id == 0) {
        // ---- TALS (k_prep outputs ready via stream order) ----
        const float* sums = g_ws + 32;
        if (t < C_N) cnt_s[t] = g_ws[8 + t];
        __syncthreads();
        for (int idx = t; idx < C_N * D_N; idx += 256) {
            int c = idx / D_N;
            cents[idx] = sums[idx] / fmaxf(cnt_s[c], 1.0f);
        }
        __syncthreads();
        // re-zero consumed sums/counts (overlapped with GEMM blocks)
        for (int idx = t; idx < C_N * D_N; idx += 256) g_ws[32 + idx] = 0.f;
        if (t < C_N) g_ws[8 + t] = 0.f;
        for (int pp = 0; pp < 25; ++pp) {
            int p = w * 25 + pp;
            int i = p / C_N, j = p - (p / C_N) * C_N;
            const float* ci = cents + i * D_N;
            const float* cj = cents + j * D_N;
            float s = 0.f;
            for (int d = lane; d < D_N; d += 64) {
                float diff = ci[d] - cj[d];
                s += diff * diff;
            }
#pragma unroll
            for (int off = 32; off; off >>= 1) s += __shfl_xor(s, off, 64);
            if (lane == 0) ed[p] = sqrtf(s + 1e-12f);
        }
        __syncthreads();
        if (w == 0) {
            float e0 = ed[lane];
            float e1 = (lane < 36) ? ed[lane + 64] : 0.f;
            float mx = fmaxf(e0, e1);
#pragma unroll
            for (int off = 32; off; off >>= 1) mx = fmaxf(mx, __shfl_xor(mx, off, 64));
            float inv = 1.0f / (mx + 1e-8f);
            float d0 = e0 * inv - topo[lane];
            float s = d0 * d0;
            if (lane < 36) {
                float d1 = e1 * inv - topo[lane + 64];
                s += d1 * d1;
            }
#pragma unroll
            for (int off = 32; off; off >>= 1) s += __shfl_xor(s, off, 64);
            if (lane == 0) {
                g_ws[2] = s * (1.0f / (C_N * C_N));
                float s2 = 0.f;
#pragma unroll
                for (int c = 0; c < C_N; ++c) s2 += cnt_s[c] * cnt_s[c];
                g_ws[3] = (float)B_N * (float)B_N - s2;
            }
        }
        __syncthreads();
        finish(out, t, id);
        return;
    }

    // triangle decode: id-1 -> (bi, bj) with bj >= bi
    int u = id - 1, bi = 0, rowlen = 32;
    while (u >= rowlen) { u -= rowlen; ++bi; --rowlen; }
    int bj = bi + u;

    int ib0 = bi * 128, jb0 = bj * 128;
    if (t < 128) lA[t] = labels[ib0 + t];
    else         lB[t - 128] = labels[jb0 + t - 128];
    if (t < C_N * C_N) topo_s[t] = topo[t];
    __syncthreads();

    int quad = lane >> 4, m16 = lane & 15;
    int wrow = (w >> 1) * 64, wcol = (w & 1) * 64;

    f32x4 acc[4][4];
    f32x4 z = {0.f, 0.f, 0.f, 0.f};
#pragma unroll
    for (int mt = 0; mt < 4; ++mt)
#pragma unroll
        for (int nt = 0; nt < 4; ++nt) acc[mt][nt] = z;

    // fragment base pointers: group-row * 768 + quad-granule * 128 + row-in-16 * 8
    const uchar* pA[4];
    const uchar* pB[4];
#pragma unroll
    for (int x = 0; x < 4; ++x) {
        pA[x] = E + (size_t)(ib0 + wrow + x * 16) * D_N + quad * 128 + m16 * 8;
        pB[x] = E + (size_t)(jb0 + wcol + x * 16) * D_N + quad * 128 + m16 * 8;
    }

#pragma unroll 2
    for (int kt = 0; kt < 12; ++kt) {
#pragma unroll
        for (int ks = 0; ks < 2; ++ks) {
            int off = kt * 1024 + ks * 512;
            long af[4], bfr[4];
#pragma unroll
            for (int x = 0; x < 4; ++x) {
                af[x]  = *(const long*)(pA[x] + off);
                bfr[x] = *(const long*)(pB[x] + off);
            }
#pragma unroll
            for (int mt = 0; mt < 4; ++mt)
#pragma unroll
                for (int nt = 0; nt < 4; ++nt)
                    acc[mt][nt] = __builtin_amdgcn_mfma_f32_16x16x32_fp8_fp8(
                        af[mt], bfr[nt], acc[mt][nt], 0, 0, 0);
        }
    }

    // epilogue: relu(sim - 1 + margin) over valid (li!=lj) upper-tri pairs, x2
    float local = 0.f;
#pragma unroll
    for (int mt = 0; mt < 4; ++mt) {
#pragma unroll
        for (int nt = 0; nt < 4; ++nt) {
#pragma unroll
            for (int reg = 0; reg < 4; ++reg) {
                int il = wrow + mt * 16 + quad * 4 + reg;
                int jl = wcol + nt * 16 + m16;
                int gi = ib0 + il, gj = jb0 + jl;
                int li = lA[il], lj = lB[jl];
                float v = acc[mt][nt][reg] - 1.0f + topo_s[li * C_N + lj];
                if (li != lj && gi < gj && v > 0.f) local += v;
            }
        }
    }
    local *= 2.0f;

#pragma unroll
    for (int off = 32; off; off >>= 1) local += __shfl_down(local, off, 64);
    if (lane == 0) wsum[w] = local;
    __syncthreads();
    if (t == 0) atomicAdd(&g_ws[7760 + 16 * (id & 7)], wsum[0] + wsum[1] + wsum[2] + wsum[3]);
    finish(out, t, id);
}

extern "C" void kernel_launch(void* const* d_in, const int* in_sizes, int n_in,
                              void* d_out, int out_size, void* d_ws, size_t ws_size,
                              hipStream_t stream) {
    const float* logits = (const float*)d_in[0];
    const int*   labels = (const int*)d_in[1];
    const float* emb    = (const float*)d_in[2];
    const float* topo   = (const float*)d_in[3];
    uchar* enorm = (uchar*)d_ws + 65536;
    float* out = (float*)d_out;

    k_prep<<<1232, 256, 0, stream>>>(logits, labels, emb, enorm);
    k_taml<<<529, 256, 0, stream>>>(enorm, labels, topo, out);
}

// Round 7
// 107.600 us; speedup vs baseline: 1.4172x; 1.0812x over previous
//
#include <hip/hip_runtime.h>
#include <hip/hip_bf16.h>
#include <math.h>

#define B_N 4096
#define D_N 768
#define C_N 10

typedef float f32x4 __attribute__((ext_vector_type(4)));
typedef unsigned char uchar;

// Self-cleaning module-scope accumulators (immune to the harness's d_ws poison;
// all-zero invariant restored by finish() at the end of every launch).
// float index map:
//   [0] ce_sum   [2] tals   [3] nvalid
//   [8..18)   counts[10]
//   [32..7712)  class sums [10][768]
//   [7760+16c] c=0..7: taml partial sums (64B-spread slots, no line sharing)
//   [7936..7944) finish sub-counters (uint), [7944] finish master
__device__ float g_ws[8192];

// d_ws byte offset 65536: enorm fp8 e4m3, FRAGMENT-TILED layout (3145728 bytes):
//   element (row r, k-byte kb) at (r & ~15)*768 + (kb>>3)*128 + (r&15)*8 + (kb&7)
// 16-row groups of 12288B; a wave's MFMA fragment load (16 rows x 4 granules)
// is one contiguous 512B region.

// ---------------- merged prep: CE + histogram | class sums | row-normalize->fp8 ----------------
// blocks [0,16): CE; [16,208): class segment sums; [208,464): enorm (block = 16-row group)
__global__ void k_prep(const float* __restrict__ logits,
                       const int* __restrict__ labels,
                       const float* __restrict__ emb,
                       uchar* __restrict__ enorm) {
    __shared__ float red[256];
    __shared__ float cnt[C_N];
    __shared__ float ls[2560];   // CE: 256x10 logits staged coalesced
    // enorm: 16 rows x 97 uint2 (pad 96->97 kills LDS bank conflicts), 12416B
    __shared__ __align__(16) unsigned int rowbuf[16 * 194];
    int bb = blockIdx.x;
    int t = threadIdx.x;

    if (bb < 16) {
        if (t < C_N) cnt[t] = 0.f;
        const float4* g4 = (const float4*)logits + bb * 640;
        float4* l4 = (float4*)ls;
        l4[t] = g4[t];
        l4[t + 256] = g4[t + 256];
        if (t < 128) l4[t + 512] = g4[t + 512];
        __syncthreads();
        int row = bb * 256 + t;
        int lab = labels[row];
        const float* lp = ls + t * C_N;   // stride-10 LDS read: 2-way alias, free
        float m = lp[0];
#pragma unroll
        for (int c = 1; c < C_N; ++c) m = fmaxf(m, lp[c]);
        float s = 0.f;
#pragma unroll
        for (int c = 0; c < C_N; ++c) s += __expf(lp[c] - m);
        float val = (m + __logf(s)) - lp[lab];
        atomicAdd(&cnt[lab], 1.0f);
        red[t] = val;
        __syncthreads();
        for (int off = 128; off; off >>= 1) {
            if (t < off) red[t] += red[t + off];
            __syncthreads();
        }
        if (t == 0) atomicAdd(&g_ws[0], red[0]);
        if (t < C_N) atomicAdd(&g_ws[8 + t], cnt[t]);
    } else if (bb < 208) {
        int bx = (bb - 16) % 3, by = (bb - 16) / 3;
        int col = bx * 256 + t;
        int rbase = by * 64;
        float a[C_N];
#pragma unroll
        for (int c = 0; c < C_N; ++c) a[c] = 0.f;
        const float* p = emb + (size_t)rbase * D_N + col;
#pragma unroll 4
        for (int rr = 0; rr < 64; ++rr) {
            int lab = labels[rbase + rr];
            float v = p[(size_t)rr * D_N];
#pragma unroll
            for (int c = 0; c < C_N; ++c) a[c] += (lab == c) ? v : 0.f;
        }
        float* sums = g_ws + 32;
#pragma unroll
        for (int c = 0; c < C_N; ++c) atomicAdd(&sums[c * D_N + col], a[c]);
    } else {
        // ---- enorm 16-row group: normalize -> LDS (padded) -> coalesced tiled store ----
        int w = t >> 6, lane = t & 63;
        int group = bb - 208;                 // 0..255
#pragma unroll
        for (int q = 0; q < 4; ++q) {
            int rr = w * 4 + q;               // row-in-group 0..15
            int row = group * 16 + rr;
            const float4* src = (const float4*)(emb + (size_t)row * D_N);
            float4 x0 = src[lane];
            float4 x1 = src[lane + 64];
            float4 x2 = src[lane + 128];
            float ss = x0.x * x0.x + x0.y * x0.y + x0.z * x0.z + x0.w * x0.w
                     + x1.x * x1.x + x1.y * x1.y + x1.z * x1.z + x1.w * x1.w
                     + x2.x * x2.x + x2.y * x2.y + x2.z * x2.z + x2.w * x2.w;
#pragma unroll
            for (int off = 32; off; off >>= 1) ss += __shfl_xor(ss, off, 64);
            float inv = 1.0f / fmaxf(sqrtf(ss), 1e-12f);
            int p0 = 0, p1 = 0, p2 = 0;
            p0 = __builtin_amdgcn_cvt_pk_fp8_f32(x0.x * inv, x0.y * inv, p0, false);
            p0 = __builtin_amdgcn_cvt_pk_fp8_f32(x0.z * inv, x0.w * inv, p0, true);
            p1 = __builtin_amdgcn_cvt_pk_fp8_f32(x1.x * inv, x1.y * inv, p1, false);
            p1 = __builtin_amdgcn_cvt_pk_fp8_f32(x1.z * inv, x1.w * inv, p1, true);
            p2 = __builtin_amdgcn_cvt_pk_fp8_f32(x2.x * inv, x2.y * inv, p2, false);
            p2 = __builtin_amdgcn_cvt_pk_fp8_f32(x2.z * inv, x2.w * inv, p2, true);
            unsigned int* rb = rowbuf + rr * 194;   // row stride 97 uint2 = 194 uints
            rb[lane]       = (unsigned int)p0;
            rb[lane + 64]  = (unsigned int)p1;
            rb[lane + 128] = (unsigned int)p2;
        }
        __syncthreads();
        // coalesced store: thread t writes 16B at group*12288 + c*4096 + t*16
        // = granule g = c*32 + (t>>3), rows r0=2*(t&7), r0+1
        uchar* gb = enorm + (size_t)group * 12288;
        const uint2* rb2 = (const uint2*)rowbuf;
#pragma unroll
        for (int c = 0; c < 3; ++c) {
            int g = c * 32 + (t >> 3);
            int r0 = 2 * (t & 7);
            uint2 lo = rb2[r0 * 97 + g];
            uint2 hi = rb2[(r0 + 1) * 97 + g];
            uint4 v = {lo.x, lo.y, hi.x, hi.y};
            *(uint4*)(gb + c * 4096 + t * 16) = v;
        }
    }
}

// finish: hierarchical end-counter; last block writes output and re-zeroes scalars.
static __device__ __forceinline__ void finish(float* __restrict__ out, int t, int id) {
    if (t == 0) {
        __threadfence();
        int c = id & 7;
        unsigned int quota = (c == 0) ? 67u : 66u;   // 529 blocks
        unsigned int p = atomicAdd((unsigned int*)&g_ws[7936 + c], 1u);
        if (p == quota - 1u) {
            unsigned int pm = atomicAdd((unsigned int*)&g_ws[7944], 1u);
            if (pm == 7u) {
                __threadfence();
                float ces  = atomicAdd(&g_ws[0], 0.0f);
                float tals = atomicAdd(&g_ws[2], 0.0f);
                float nv   = atomicAdd(&g_ws[3], 0.0f);
                float tsum = 0.f;
#pragma unroll
                for (int i = 0; i < 8; ++i) tsum += atomicAdd(&g_ws[7760 + 16 * i], 0.0f);
                float ce   = ces / (float)B_N;
                float taml = tsum / fmaxf(nv, 1.0f);
                out[0] = ce + 0.5f * tals + 0.5f * taml;
                out[1] = ce;
                out[2] = tals;
                out[3] = taml;
#pragma unroll
                for (int i = 0; i < 8; ++i) g_ws[i] = 0.f;
#pragma unroll
                for (int i = 0; i < 8; ++i) g_ws[7760 + 16 * i] = 0.f;
#pragma unroll
                for (int i = 0; i < 9; ++i) g_ws[7936 + i] = 0.f;
            }
        }
    }
}

// ---------------- TAML GEMM: register-direct fp8 MFMA, NO LDS staging, NO barriers ----------------
// 529 blocks: id 0 = TALS; id 1..528 = upper-tri 128x128 tiles. enorm (3MB) is
// L2/L3-resident; fragment-tiled layout makes every A/B fragment load one coalesced
// 512B wave-load. K-loop = 24 x {8 loads, 16 MFMAs}, #pragma unroll 4 keeps 3-4
// load batches in flight (~640+ cyc coverage > L3 first-touch latency). VGPRs free
// at ~2 blocks/CU (block-count-limited), so launch_bounds(256,2) allows deep unroll.
__global__ __launch_bounds__(256, 2) void k_taml(const uchar* __restrict__ E,
                                                 const int* __restrict__ labels,
                                                 const float* __restrict__ topo,
                                                 float* __restrict__ out) {
    __shared__ float cents[C_N * D_N];   // 30KB, TALS block only
    __shared__ int lA[128], lB[128];
    __shared__ float topo_s[C_N * C_N];
    __shared__ float wsum[4];
    __shared__ float ed[112];
    __shared__ float cnt_s[C_N];

    int t = threadIdx.x;
    int w = t >> 6, lane = t & 63;
    int id = blockIdx.x;

    if (id == 0) {
        // ---- TALS (k_prep outputs ready via stream order) ----
        const float* sums = g_ws + 32;
        if (t < C_N) cnt_s[t] = g_ws[8 + t];
        __syncthreads();
        for (int idx = t; idx < C_N * D_N; idx += 256) {
            int c = idx / D_N;
            cents[idx] = sums[idx] / fmaxf(cnt_s[c], 1.0f);
        }
        __syncthreads();
        for (int idx = t; idx < C_N * D_N; idx += 256) g_ws[32 + idx] = 0.f;
        if (t < C_N) g_ws[8 + t] = 0.f;
        for (int pp = 0; pp < 25; ++pp) {
            int p = w * 25 + pp;
            int i = p / C_N, j = p - (p / C_N) * C_N;
            const float* ci = cents + i * D_N;
            const float* cj = cents + j * D_N;
            float s = 0.f;
            for (int d = lane; d < D_N; d += 64) {
                float diff = ci[d] - cj[d];
                s += diff * diff;
            }
#pragma unroll
            for (int off = 32; off; off >>= 1) s += __shfl_xor(s, off, 64);
            if (lane == 0) ed[p] = sqrtf(s + 1e-12f);
        }
        __syncthreads();
        if (w == 0) {
            float e0 = ed[lane];
            float e1 = (lane < 36) ? ed[lane + 64] : 0.f;
            float mx = fmaxf(e0, e1);
#pragma unroll
            for (int off = 32; off; off >>= 1) mx = fmaxf(mx, __shfl_xor(mx, off, 64));
            float inv = 1.0f / (mx + 1e-8f);
            float d0 = e0 * inv - topo[lane];
            float s = d0 * d0;
            if (lane < 36) {
                float d1 = e1 * inv - topo[lane + 64];
                s += d1 * d1;
            }
#pragma unroll
            for (int off = 32; off; off >>= 1) s += __shfl_xor(s, off, 64);
            if (lane == 0) {
                g_ws[2] = s * (1.0f / (C_N * C_N));
                float s2 = 0.f;
#pragma unroll
                for (int c = 0; c < C_N; ++c) s2 += cnt_s[c] * cnt_s[c];
                g_ws[3] = (float)B_N * (float)B_N - s2;
            }
        }
        __syncthreads();
        finish(out, t, id);
        return;
    }

    // triangle decode: id-1 -> (bi, bj) with bj >= bi
    int u = id - 1, bi = 0, rowlen = 32;
    while (u >= rowlen) { u -= rowlen; ++bi; --rowlen; }
    int bj = bi + u;

    int ib0 = bi * 128, jb0 = bj * 128;
    if (t < 128) lA[t] = labels[ib0 + t];
    else         lB[t - 128] = labels[jb0 + t - 128];
    if (t < C_N * C_N) topo_s[t] = topo[t];
    __syncthreads();

    int quad = lane >> 4, m16 = lane & 15;
    int wrow = (w >> 1) * 64, wcol = (w & 1) * 64;

    f32x4 acc[4][4];
    f32x4 z = {0.f, 0.f, 0.f, 0.f};
#pragma unroll
    for (int mt = 0; mt < 4; ++mt)
#pragma unroll
        for (int nt = 0; nt < 4; ++nt) acc[mt][nt] = z;

    // fragment base pointers: group-row * 768 + quad-granule * 128 + row-in-16 * 8
    const uchar* pA[4];
    const uchar* pB[4];
#pragma unroll
    for (int x = 0; x < 4; ++x) {
        pA[x] = E + (size_t)(ib0 + wrow + x * 16) * D_N + quad * 128 + m16 * 8;
        pB[x] = E + (size_t)(jb0 + wcol + x * 16) * D_N + quad * 128 + m16 * 8;
    }

    // 24 K-steps of K=32 each; unroll 4 -> 3-4 batches of 8 loads in flight
#pragma unroll 4
    for (int ks24 = 0; ks24 < 24; ++ks24) {
        int off = ks24 * 512;
        long af[4], bfr[4];
#pragma unroll
        for (int x = 0; x < 4; ++x) {
            af[x]  = *(const long*)(pA[x] + off);
            bfr[x] = *(const long*)(pB[x] + off);
        }
#pragma unroll
        for (int mt = 0; mt < 4; ++mt)
#pragma unroll
            for (int nt = 0; nt < 4; ++nt)
                acc[mt][nt] = __builtin_amdgcn_mfma_f32_16x16x32_fp8_fp8(
                    af[mt], bfr[nt], acc[mt][nt], 0, 0, 0);
    }

    // epilogue: relu(sim - 1 + margin) over valid (li!=lj) upper-tri pairs, x2
    float local = 0.f;
#pragma unroll
    for (int mt = 0; mt < 4; ++mt) {
#pragma unroll
        for (int nt = 0; nt < 4; ++nt) {
#pragma unroll
            for (int reg = 0; reg < 4; ++reg) {
                int il = wrow + mt * 16 + quad * 4 + reg;
                int jl = wcol + nt * 16 + m16;
                int gi = ib0 + il, gj = jb0 + jl;
                int li = lA[il], lj = lB[jl];
                float v = acc[mt][nt][reg] - 1.0f + topo_s[li * C_N + lj];
                if (li != lj && gi < gj && v > 0.f) local += v;
            }
        }
    }
    local *= 2.0f;

#pragma unroll
    for (int off = 32; off; off >>= 1) local += __shfl_down(local, off, 64);
    if (lane == 0) wsum[w] = local;
    __syncthreads();
    if (t == 0) atomicAdd(&g_ws[7760 + 16 * (id & 7)], wsum[0] + wsum[1] + wsum[2] + wsum[3]);
    finish(out, t, id);
}

extern "C" void kernel_launch(void* const* d_in, const int* in_sizes, int n_in,
                              void* d_out, int out_size, void* d_ws, size_t ws_size,
                              hipStream_t stream) {
    const float* logits = (const float*)d_in[0];
    const int*   labels = (const int*)d_in[1];
    const float* emb    = (const float*)d_in[2];
    const float* topo   = (const float*)d_in[3];
    uchar* enorm = (uchar*)d_ws + 65536;
    float* out = (float*)d_out;

    k_prep<<<464, 256, 0, stream>>>(logits, labels, emb, enorm);
    k_taml<<<529, 256, 0, stream>>>(enorm, labels, topo, out);
}